// Round 4
// baseline (282.860 us; speedup 1.0000x reference)
//
#include <hip/hip_runtime.h>
#include <hip/hip_bf16.h>
#include <stdint.h>
#include <stddef.h>

#define M_DIM 8192
#define N_DIM 4096
#define K_DIM 4096

typedef float f32x4 __attribute__((ext_vector_type(4)));
typedef float f32x16 __attribute__((ext_vector_type(16)));
typedef __bf16 bf16x8 __attribute__((ext_vector_type(8)));
typedef unsigned short u16x8 __attribute__((ext_vector_type(8)));

__device__ inline unsigned short f2bf_rne(float f) {
    unsigned int u = __builtin_bit_cast(unsigned int, f);
    u += 0x7fffu + ((u >> 16) & 1u);
    return (unsigned short)(u >> 16);
}

__device__ inline unsigned short sgn_bf16(float v) {
    return (v > 0.f) ? (unsigned short)0x3F80u : ((v < 0.f) ? (unsigned short)0xBF80u : (unsigned short)0u);
}

// merged conversion: x -> bf16 (RNE), w -> sign bf16; one launch
__global__ void __launch_bounds__(256) cvt_all_kernel(const float* __restrict__ x,
                                                      const float* __restrict__ w,
                                                      u16x8* __restrict__ xb,
                                                      u16x8* __restrict__ wb,
                                                      int n8x, int n8tot) {
    int i = blockIdx.x * 256 + threadIdx.x;
    const int stride = gridDim.x * 256;
    for (; i < n8tot; i += stride) {
        if (i < n8x) {
            const f32x4* p = reinterpret_cast<const f32x4*>(x) + (size_t)i * 2;
            f32x4 a = p[0];
            f32x4 b = p[1];
            u16x8 o;
            o[0] = f2bf_rne(a[0]); o[1] = f2bf_rne(a[1]);
            o[2] = f2bf_rne(a[2]); o[3] = f2bf_rne(a[3]);
            o[4] = f2bf_rne(b[0]); o[5] = f2bf_rne(b[1]);
            o[6] = f2bf_rne(b[2]); o[7] = f2bf_rne(b[3]);
            xb[i] = o;
        } else {
            int j = i - n8x;
            const f32x4* p = reinterpret_cast<const f32x4*>(w) + (size_t)j * 2;
            f32x4 a = p[0];
            f32x4 b = p[1];
            u16x8 o;
            o[0] = sgn_bf16(a[0]); o[1] = sgn_bf16(a[1]);
            o[2] = sgn_bf16(a[2]); o[3] = sgn_bf16(a[3]);
            o[4] = sgn_bf16(b[0]); o[5] = sgn_bf16(b[1]);
            o[6] = sgn_bf16(b[2]); o[7] = sgn_bf16(b[3]);
            wb[j] = o;
        }
    }
}

// ---------------------------------------------------------------------------
// 256x256 8-phase bf16 GEMM, round 4: 32x32x16 MFMA (1015 FLOP/cyc/SIMD vs
// 844 for 16x16x32). Same 8-phase skeleton, counted vmcnt(4), setprio, 8-way
// row-XOR LDS swizzle. Per wave 128x64 out = 4Mx2N 32x32 tiles; per K-tile
// (BK=64) 4 k-steps; quads: (qm in {mi01, mi23}) x (qn in {ni0, ni1}),
// 8 MFMA per phase.
// A/B frag (32x32x16 bf16): row = lane&31, k = (lane>>5)*8 + j.
// C/D frag (m74/m101): col = lane&31, row = (reg&3) + 8*(reg>>2) + 4*(lane>>5).
// Swizzle: phys_16B_blk = logical ^ (row&7); logical = ks*2 + (lane>>5)
//   => byte off = 16*((lane>>5)^(lane&1)) + 32*(ks^((lane>>1)&3)).
// ---------------------------------------------------------------------------

#define BAR() do { asm volatile("" ::: "memory"); __builtin_amdgcn_s_barrier(); asm volatile("" ::: "memory"); } while (0)
#define WLG0() asm volatile("s_waitcnt lgkmcnt(0)" ::: "memory")
#define WVM(n) asm volatile("s_waitcnt vmcnt(" #n ")" ::: "memory")

#define STAGE_A(d, kt, h) do { \
    const unsigned short* _g = aSrc + (size_t)((h) * 128) * K_DIM + (size_t)(kt) * 64; \
    __builtin_amdgcn_global_load_lds((const __attribute__((address_space(1))) void*)_g, \
        (__attribute__((address_space(3))) void*)(smem + (d) * 65536 + (h) * 16384 + wave * 1024), 16, 0, 0); \
    __builtin_amdgcn_global_load_lds((const __attribute__((address_space(1))) void*)(_g + (size_t)64 * K_DIM), \
        (__attribute__((address_space(3))) void*)(smem + (d) * 65536 + (h) * 16384 + 8192 + wave * 1024), 16, 0, 0); \
} while (0)

#define STAGE_B(d, kt, h) do { \
    const unsigned short* _g = bSrc + (size_t)((h) * 128) * K_DIM + (size_t)(kt) * 64; \
    __builtin_amdgcn_global_load_lds((const __attribute__((address_space(1))) void*)_g, \
        (__attribute__((address_space(3))) void*)(smem + (d) * 65536 + 32768 + (h) * 16384 + wave * 1024), 16, 0, 0); \
    __builtin_amdgcn_global_load_lds((const __attribute__((address_space(1))) void*)(_g + (size_t)64 * K_DIM), \
        (__attribute__((address_space(3))) void*)(smem + (d) * 65536 + 32768 + (h) * 16384 + 8192 + wave * 1024), 16, 0, 0); \
} while (0)

// load A fragments for mi-pair qm (local mi 0,1 -> global mi qm*2+miL), all 4 ks
#define LOAD_AQ(sAc, qm) do { \
    _Pragma("unroll") \
    for (int _miL = 0; _miL < 2; ++_miL) \
    _Pragma("unroll") \
    for (int _ks = 0; _ks < 4; ++_ks) \
        aF[_miL][_ks] = *(const bf16x8*)((sAc) + aOff[_ks] + ((qm) * 2 + _miL) * 4096); \
} while (0)

// load B fragments for ni = qn, all 4 ks
#define LOAD_BQ(sBc, qn) do { \
    _Pragma("unroll") \
    for (int _ks = 0; _ks < 4; ++_ks) \
        bF[qn][_ks] = *(const bf16x8*)((sBc) + bOff[_ks] + (qn) * 4096); \
} while (0)

#define MFMA_Q(qm, qn) do { \
    __builtin_amdgcn_s_setprio(1); \
    _Pragma("unroll") \
    for (int _miL = 0; _miL < 2; ++_miL) \
    _Pragma("unroll") \
    for (int _ks = 0; _ks < 4; ++_ks) \
        acc[(qm) * 2 + _miL][qn] = __builtin_amdgcn_mfma_f32_32x32x16_bf16( \
            aF[_miL][_ks], bF[qn][_ks], acc[(qm) * 2 + _miL][qn], 0, 0, 0); \
    __builtin_amdgcn_s_setprio(0); \
} while (0)

__global__ void __launch_bounds__(512, 2) gemm_bin_256(
        const unsigned short* __restrict__ A,   // [M][K] bf16 bits
        const unsigned short* __restrict__ B,   // [N][K] bf16 bits (sign weights)
        const float* __restrict__ bias,
        float* __restrict__ C) {
    __shared__ __align__(16) char smem[131072];

    const int tid  = threadIdx.x;
    const int lane = tid & 63;
    const int wave = tid >> 6;
    const int wm = wave >> 2;      // 0..1
    const int wn = wave & 3;       // 0..3

    // XCD-bijective swizzle: nwg=512, 512/8=64 per XCD
    const int wgid = (blockIdx.x & 7) * 64 + (blockIdx.x >> 3);
    const int m0 = (wgid >> 4) * 256;   // 32 m-tiles
    const int n0 = (wgid & 15) * 256;   // 16 n-tiles

    // staging: thread t writes LDS linear t*16B => row t/8, phys blk t%8;
    // source carries the inverse swizzle
    const int srow = tid >> 3;          // 0..63
    const int scolblk = (tid & 7) ^ (srow & 7);
    const unsigned short* aSrc = A + (size_t)(m0 + srow) * K_DIM + scolblk * 8;
    const unsigned short* bSrc = B + (size_t)(n0 + srow) * K_DIM + scolblk * 8;

    // ds_read addressing (32x32 frags)
    const int r31 = lane & 31;
    const int hi  = lane >> 5;
    const int e0  = lane & 1;
    const int e12 = (lane >> 1) & 3;
    const int aBase = (wm * 128 + r31) * 128 + 16 * (hi ^ e0);
    const int bBase = (wn * 64 + r31) * 128 + 16 * (hi ^ e0);
    int aOff[4], bOff[4];
    #pragma unroll
    for (int ks = 0; ks < 4; ++ks) {
        const int o = 32 * (ks ^ e12);
        aOff[ks] = aBase + o;
        bOff[ks] = bBase + o;
    }

    const char* sA0 = smem;
    const char* sB0 = smem + 32768;
    const char* sA1 = smem + 65536;
    const char* sB1 = smem + 98304;

    bf16x8 aF[2][4];
    bf16x8 bF[2][4];
    f32x16 acc[4][2];
    #pragma unroll
    for (int i = 0; i < 4; ++i)
        #pragma unroll
        for (int j = 0; j < 2; ++j)
            acc[i][j] = (f32x16)(0.f);

    // prologue: B(0), A(0) -> dbuf0; B(1) -> dbuf1; leave B(1) pair in flight
    STAGE_B(0, 0, 0); STAGE_B(0, 0, 1);
    STAGE_A(0, 0, 0); STAGE_A(0, 0, 1);
    STAGE_B(1, 1, 0); STAGE_B(1, 1, 1);
    WVM(4); BAR();

    for (int it = 0; it < 31; ++it) {
        const int k1 = 2 * it + 1, k2 = 2 * it + 2, k3 = 2 * it + 3;
        // ph0: K-tile 2it quad (qm0, qn0)
        LOAD_BQ(sB0, 0); LOAD_AQ(sA0, 0); STAGE_A(1, k1, 0);
        BAR(); MFMA_Q(0, 0); WLG0(); BAR();
        // ph1: quad (qm0, qn1)
        LOAD_BQ(sB0, 1); STAGE_A(1, k1, 1);
        BAR(); MFMA_Q(0, 1); WLG0(); BAR();
        // ph2: quad (qm1, qn1)
        LOAD_AQ(sA0, 1); STAGE_B(0, k2, 0);
        BAR(); MFMA_Q(1, 1); WLG0(); BAR();
        // ph3: quad (qm1, qn0); counted wait -> K-tile 2it+1 fully landed
        STAGE_B(0, k2, 1); WVM(4);
        BAR(); MFMA_Q(1, 0); BAR();
        // ph4: K-tile 2it+1 quad (qm0, qn0)
        LOAD_BQ(sB1, 0); LOAD_AQ(sA1, 0); STAGE_A(0, k2, 0);
        BAR(); MFMA_Q(0, 0); WLG0(); BAR();
        // ph5
        LOAD_BQ(sB1, 1); STAGE_A(0, k2, 1);
        BAR(); MFMA_Q(0, 1); WLG0(); BAR();
        // ph6
        LOAD_AQ(sA1, 1); STAGE_B(1, k3, 0);
        BAR(); MFMA_Q(1, 1); WLG0(); BAR();
        // ph7: counted wait -> K-tile 2it+2 fully landed
        STAGE_B(1, k3, 1); WVM(4);
        BAR(); MFMA_Q(1, 0); BAR();
    }

    // final iteration: K-tiles 62 (dbuf0), 63 (dbuf1); stage only A(63)
    LOAD_BQ(sB0, 0); LOAD_AQ(sA0, 0); STAGE_A(1, 63, 0);
    BAR(); MFMA_Q(0, 0); WLG0(); BAR();
    LOAD_BQ(sB0, 1); STAGE_A(1, 63, 1);
    BAR(); MFMA_Q(0, 1); WLG0(); BAR();
    LOAD_AQ(sA0, 1);
    BAR(); MFMA_Q(1, 1); WLG0(); BAR();
    WVM(0);
    BAR(); MFMA_Q(1, 0); BAR();
    LOAD_BQ(sB1, 0); LOAD_AQ(sA1, 0);
    BAR(); MFMA_Q(0, 0); WLG0(); BAR();
    LOAD_BQ(sB1, 1);
    BAR(); MFMA_Q(0, 1); WLG0(); BAR();
    LOAD_AQ(sA1, 1);
    BAR(); MFMA_Q(1, 1); WLG0(); BAR();
    MFMA_Q(1, 0);

    // epilogue: 32x32 C/D layout col = lane&31, row = (reg&3)+8*(reg>>2)+4*(lane>>5)
    const int ecol = n0 + wn * 64 + r31;
    const int erow_base = m0 + wm * 128 + 4 * hi;
    #pragma unroll
    for (int mi = 0; mi < 4; ++mi) {
        #pragma unroll
        for (int ni = 0; ni < 2; ++ni) {
            const float bv = bias[ecol + ni * 32];
            #pragma unroll
            for (int rg = 0; rg < 4; ++rg)
                #pragma unroll
                for (int j = 0; j < 4; ++j) {
                    const int row = erow_base + mi * 32 + rg * 8 + j;
                    C[(size_t)row * N_DIM + ecol + ni * 32] = acc[mi][ni][rg * 4 + j] + bv;
                }
        }
    }
}

// ---- correctness fallback if workspace is too small (not expected) ----
__global__ void __launch_bounds__(256) fallback_kernel(const float* __restrict__ x,
        const float* __restrict__ w, const float* __restrict__ bias,
        float* __restrict__ out) {
    const size_t idx = (size_t)blockIdx.x * 256 + threadIdx.x;
    const int m = (int)(idx / N_DIM);
    const int n = (int)(idx % N_DIM);
    const float* xr = x + (size_t)m * K_DIM;
    const float* wr = w + (size_t)n * K_DIM;
    float s = 0.f;
    for (int k = 0; k < K_DIM; k += 4) {
        f32x4 a = *reinterpret_cast<const f32x4*>(xr + k);
        f32x4 b = *reinterpret_cast<const f32x4*>(wr + k);
        #pragma unroll
        for (int j = 0; j < 4; ++j)
            s += (b[j] > 0.f) ? a[j] : ((b[j] < 0.f) ? -a[j] : 0.f);
    }
    out[idx] = s + bias[n];
}

extern "C" void kernel_launch(void* const* d_in, const int* in_sizes, int n_in,
                              void* d_out, int out_size, void* d_ws, size_t ws_size,
                              hipStream_t stream) {
    const float* x    = (const float*)d_in[0];
    const float* w    = (const float*)d_in[1];
    const float* bias = (const float*)d_in[2];
    float* out = (float*)d_out;

    const size_t a_bytes = (size_t)M_DIM * K_DIM * 2;   // 67.1 MB
    const size_t w_bytes = (size_t)N_DIM * K_DIM * 2;   // 33.6 MB

    if (ws_size >= a_bytes + w_bytes) {
        unsigned short* xb = (unsigned short*)d_ws;
        unsigned short* wb = (unsigned short*)((char*)d_ws + a_bytes);

        const int n8x = (M_DIM * K_DIM) / 8;
        const int n8w = (N_DIM * K_DIM) / 8;
        cvt_all_kernel<<<2048, 256, 0, stream>>>(x, w, (u16x8*)xb, (u16x8*)wb,
                                                 n8x, n8x + n8w);

        gemm_bin_256<<<512, 512, 0, stream>>>(xb, wb, bias, out);
    } else {
        fallback_kernel<<<(M_DIM * (N_DIM / 256)), 256, 0, stream>>>(x, w, bias, out);
    }
}